// Round 1
// baseline (88.507 us; speedup 1.0000x reference)
//
#include <hip/hip_runtime.h>

// out[i, 7n+o, m] = sum_{j,k} x[j, 7n+o+k-1, m] * W[i,j,k], taps clipped to o+k-1 in [0,7)
// x: (48,56,56) f32, W: (192,48,3) f32, out: (192,56,56) f32

#define CH_IN 48
#define CH_OUT 192
#define HW 56
#define SP 3136   // 56*56
#define NB 8      // number of 7-row blocks
#define OB 7      // rows per block
#define M4 14     // float4 chunks per 56-wide row
#define COLS (NB * M4)          // 112 columns per output channel
#define TOTAL (CH_OUT * COLS)   // 21504 threads

__device__ __forceinline__ void fma4(float4& a, float s, const float4& b) {
    a.x += s * b.x; a.y += s * b.y; a.z += s * b.z; a.w += s * b.w;
}

__global__ __launch_bounds__(64) void conv_unfold_kernel(const float* __restrict__ x,
                                                         const float* __restrict__ W,
                                                         float* __restrict__ out) {
    int tid = blockIdx.x * 64 + threadIdx.x;
    if (tid >= TOTAL) return;

    const int i   = tid / COLS;        // output channel
    const int rem = tid % COLS;
    const int n   = rem / M4;          // 7-row block index
    const int m4  = rem % M4;          // float4 index along width

    const float* xcol = x + n * (OB * HW) + m4 * 4;
    const float* wrow = W + i * (CH_IN * 3);

    float4 acc[OB];
#pragma unroll
    for (int o = 0; o < OB; ++o) acc[o] = make_float4(0.f, 0.f, 0.f, 0.f);

    for (int j = 0; j < CH_IN; ++j) {
        const float w0 = wrow[j * 3 + 0];
        const float w1 = wrow[j * 3 + 1];
        const float w2 = wrow[j * 3 + 2];

        float4 xv[OB];
        const float* xj = xcol + j * SP;
#pragma unroll
        for (int o = 0; o < OB; ++o)
            xv[o] = *reinterpret_cast<const float4*>(xj + o * HW);

#pragma unroll
        for (int o = 0; o < OB; ++o) {
            if (o > 0)      fma4(acc[o], w0, xv[o - 1]);  // k=0 tap (row o-1)
            fma4(acc[o], w1, xv[o]);                      // k=1 tap
            if (o < OB - 1) fma4(acc[o], w2, xv[o + 1]);  // k=2 tap (row o+1)
        }
    }

    float* ocol = out + i * SP + n * (OB * HW) + m4 * 4;
#pragma unroll
    for (int o = 0; o < OB; ++o)
        *reinterpret_cast<float4*>(ocol + o * HW) = acc[o];
}

extern "C" void kernel_launch(void* const* d_in, const int* in_sizes, int n_in,
                              void* d_out, int out_size, void* d_ws, size_t ws_size,
                              hipStream_t stream) {
    const float* x = (const float*)d_in[0];
    const float* W = (const float*)d_in[1];
    float* out = (float*)d_out;

    const int block = 64;
    const int grid = (TOTAL + block - 1) / block;  // 336 single-wave blocks
    conv_unfold_kernel<<<grid, block, 0, stream>>>(x, W, out);
}

// Round 2
// 62.226 us; speedup vs baseline: 1.4224x; 1.4224x over previous
//
#include <hip/hip_runtime.h>

// out[i, 7n+o, m] = sum_{j,k} x[j, 7n+o+k-1, m] * W[i,j,k], taps clipped to o+k-1 in [0,7)
// x: (48,56,56) f32, W: (192,48,3) f32, out: (192,56,56) f32
//
// R1: split-j(4) + LDS reduce. 256-thread block = 64 columns x 4 j-segments.
// Each thread: 12 input channels of one (i,n,m4) 7-row column.

#define CH_IN 48
#define CH_OUT 192
#define HW 56
#define SP 3136   // 56*56
#define NB 8      // number of 7-row blocks
#define OB 7      // rows per block
#define M4 14     // float4 chunks per 56-wide row
#define COLS (NB * M4)            // 112 columns per output channel
#define NCOL (CH_OUT * COLS)      // 21504 columns total
#define SEGS 4
#define JSEG (CH_IN / SEGS)       // 12 input channels per segment

__device__ __forceinline__ void fma4(float4& a, float s, const float4& b) {
    a.x += s * b.x; a.y += s * b.y; a.z += s * b.z; a.w += s * b.w;
}
__device__ __forceinline__ void add4(float4& a, const float4& b) {
    a.x += b.x; a.y += b.y; a.z += b.z; a.w += b.w;
}

__global__ __launch_bounds__(256) void conv_split_kernel(const float* __restrict__ x,
                                                         const float* __restrict__ W,
                                                         float* __restrict__ out) {
    __shared__ float4 lds[SEGS][OB][64];   // 28 KB

    const int c   = threadIdx.x & 63;      // column within block
    const int seg = threadIdx.x >> 6;      // j-segment
    const int col = blockIdx.x * 64 + c;   // global column, grid covers NCOL exactly

    const int i   = col / COLS;            // output channel
    const int rem = col % COLS;
    const int n   = rem / M4;              // 7-row block
    const int m4  = rem % M4;              // float4 index along width

    const float* xcol = x + seg * (JSEG * SP) + n * (OB * HW) + m4 * 4;
    const float* wrow = W + i * (CH_IN * 3) + seg * (JSEG * 3);

    float4 acc[OB];
#pragma unroll
    for (int o = 0; o < OB; ++o) acc[o] = make_float4(0.f, 0.f, 0.f, 0.f);

#pragma unroll 4
    for (int j = 0; j < JSEG; ++j) {
        const float w0 = wrow[j * 3 + 0];
        const float w1 = wrow[j * 3 + 1];
        const float w2 = wrow[j * 3 + 2];

        const float* xj = xcol + j * SP;
        float4 xv[OB];
#pragma unroll
        for (int o = 0; o < OB; ++o)
            xv[o] = *reinterpret_cast<const float4*>(xj + o * HW);

#pragma unroll
        for (int o = 0; o < OB; ++o) {
            if (o > 0)      fma4(acc[o], w0, xv[o - 1]);  // k=0 tap
            fma4(acc[o], w1, xv[o]);                      // k=1 tap
            if (o < OB - 1) fma4(acc[o], w2, xv[o + 1]);  // k=2 tap
        }
    }

#pragma unroll
    for (int o = 0; o < OB; ++o) lds[seg][o][c] = acc[o];
    __syncthreads();

    // Reduce 4 segments for the block's 7*64 = 448 float4 outputs using 256 threads.
    for (int t = threadIdx.x; t < OB * 64; t += 256) {
        const int o  = t >> 6;
        const int cc = t & 63;
        float4 s = lds[0][o][cc];
        add4(s, lds[1][o][cc]);
        add4(s, lds[2][o][cc]);
        add4(s, lds[3][o][cc]);

        const int col2 = blockIdx.x * 64 + cc;
        const int i2   = col2 / COLS;
        const int rem2 = col2 % COLS;
        const int n2   = rem2 / M4;
        const int m42  = rem2 % M4;
        *reinterpret_cast<float4*>(out + i2 * SP + n2 * (OB * HW) + o * HW + m42 * 4) = s;
    }
}

extern "C" void kernel_launch(void* const* d_in, const int* in_sizes, int n_in,
                              void* d_out, int out_size, void* d_ws, size_t ws_size,
                              hipStream_t stream) {
    const float* x = (const float*)d_in[0];
    const float* W = (const float*)d_in[1];
    float* out = (float*)d_out;

    const int grid = NCOL / 64;  // 336 blocks x 256 threads (4 waves each)
    conv_split_kernel<<<grid, 256, 0, stream>>>(x, W, out);
}